// Round 12
// baseline (342.236 us; speedup 1.0000x reference)
//
#include <hip/hip_runtime.h>
#include <hip/hip_bf16.h>
#include <hip/hip_fp16.h>

#define FIN 256
#define HID 128
#define BSH 7            // bucket = dst >> 7 (128 nodes/bucket)
#define NBK_MAX 1024
#define EPB 4096         // edges per block in hist/pair kernels
#define WPAD 264         // 256 + 8 halfs row pad

typedef __attribute__((ext_vector_type(8))) _Float16 half8v;  // f16x8 MFMA frag (4 VGPRs)
typedef __attribute__((ext_vector_type(4))) float f32x4;      // MFMA acc

// ---------------- bucket histogram via LDS ----------------
__global__ __launch_bounds__(256) void k_hist(const int* __restrict__ dst, int* __restrict__ bcnt,
                                              int nbk, int e) {
    __shared__ int cnt[NBK_MAX];
    int t = threadIdx.x;
    for (int b = t; b < nbk; b += 256) cnt[b] = 0;
    __syncthreads();
    int e0 = blockIdx.x * EPB;
    #pragma unroll
    for (int j = 0; j < EPB; j += 256) {
        int idx = e0 + j + t;
        if (idx < e) atomicAdd(&cnt[dst[idx] >> BSH], 1);
    }
    __syncthreads();
    for (int b = t; b < nbk; b += 256)
        if (cnt[b]) atomicAdd(&bcnt[b], cnt[b]);
}

// ---------------- bucket scan (single block) ----------------
__global__ __launch_bounds__(1024) void k_bscan(const int* __restrict__ bcnt, int* __restrict__ bo,
                                                int* __restrict__ bcur, int nbk, int e) {
    __shared__ int sm[1024];
    int t = threadIdx.x;
    int v = (t < nbk) ? bcnt[t] : 0;
    sm[t] = v;
    __syncthreads();
    int acc = v;
    for (int off = 1; off < 1024; off <<= 1) {
        int u = (t >= off) ? sm[t - off] : 0;
        __syncthreads();
        acc += u;
        sm[t] = acc;
        __syncthreads();
    }
    if (t < nbk) { bo[t] = acc - v; bcur[t] = acc - v; }
    if (t == 0) bo[nbk] = e;
}

// ---------------- two-phase pair scatter (LDS counts, 1 global atomic per block-bucket) ----------------
__global__ __launch_bounds__(256) void k_pair2(const int* __restrict__ src, const int* __restrict__ dst,
                                               int* __restrict__ bcur, int2* __restrict__ pairs,
                                               int nbk, int e) {
    __shared__ int cnt[NBK_MAX];
    __shared__ int base[NBK_MAX];
    const int t = threadIdx.x;
    for (int b = t; b < nbk; b += 256) cnt[b] = 0;
    __syncthreads();
    const int e0 = blockIdx.x * EPB;
    int s[16], d[16], lo[16];
    #pragma unroll
    for (int j = 0; j < 16; ++j) {
        int idx = e0 + j * 256 + t;
        if (idx < e) {
            s[j] = src[idx];
            d[j] = dst[idx];
            lo[j] = atomicAdd(&cnt[d[j] >> BSH], 1);
        }
    }
    __syncthreads();
    for (int b = t; b < nbk; b += 256)
        base[b] = cnt[b] ? atomicAdd(&bcur[b], cnt[b]) : 0;
    __syncthreads();
    #pragma unroll
    for (int j = 0; j < 16; ++j) {
        int idx = e0 + j * 256 + t;
        if (idx < e) pairs[base[d[j] >> BSH] + lo[j]] = make_int2(s[j], d[j]);
    }
}

// ---------------- per-bucket degree (LDS histogram, plain stores) ----------------
__global__ __launch_bounds__(256) void k_bdeg(const int2* __restrict__ pairs, const int* __restrict__ bo,
                                              int* __restrict__ deg, int n) {
    __shared__ int cnt[128];
    const int b = blockIdx.x, t = threadIdx.x;
    if (t < 128) cnt[t] = 0;
    __syncthreads();
    int beg = bo[b], end = bo[b + 1];
    for (int i = beg + t; i < end; i += 256) atomicAdd(&cnt[pairs[i].y & 127], 1);
    __syncthreads();
    int node = (b << BSH) + t;
    if (t < 128 && node < n) deg[node] = cnt[t];
}

// ---------------- 3-kernel exclusive scan over deg ----------------
__global__ __launch_bounds__(256) void k_scan1(const int* __restrict__ deg, int* __restrict__ partial,
                                               int* __restrict__ bsum, int n) {
    __shared__ int sm[256];
    int t = threadIdx.x;
    int i = blockIdx.x * 256 + t;
    int v = (i < n) ? deg[i] : 0;
    sm[t] = v;
    __syncthreads();
    int acc = v;
    for (int off = 1; off < 256; off <<= 1) {
        int u = (t >= off) ? sm[t - off] : 0;
        __syncthreads();
        acc += u;
        sm[t] = acc;
        __syncthreads();
    }
    if (i < n) partial[i] = acc;
    if (t == 255) bsum[blockIdx.x] = acc;
}

__global__ __launch_bounds__(512) void k_scan2(const int* __restrict__ bsum, int* __restrict__ boff, int nb) {
    __shared__ int sm[512];
    int t = threadIdx.x;
    int v = (t < nb) ? bsum[t] : 0;
    sm[t] = v;
    __syncthreads();
    int acc = v;
    for (int off = 1; off < 512; off <<= 1) {
        int u = (t >= off) ? sm[t - off] : 0;
        __syncthreads();
        acc += u;
        sm[t] = acc;
        __syncthreads();
    }
    if (t < nb) boff[t] = acc - v;
}

__global__ __launch_bounds__(256) void k_scan3(const int* __restrict__ deg, const int* __restrict__ partial,
                                               const int* __restrict__ boff, int* __restrict__ rowptr,
                                               float* __restrict__ dinv, int n, int e) {
    int i = blockIdx.x * 256 + threadIdx.x;
    if (i >= n) return;
    rowptr[i] = boff[blockIdx.x] + partial[i] - deg[i];
    dinv[i] = rsqrtf((float)(deg[i] + 1));
    if (i == 0) rowptr[n] = e;
}

// ---------------- per-bucket CSR fill (LDS cursors seeded from rowptr) ----------------
__global__ __launch_bounds__(256) void k_bfill(const int2* __restrict__ pairs, const int* __restrict__ bo,
                                               const int* __restrict__ rowptr, int* __restrict__ csr_src,
                                               int n) {
    __shared__ int cur[128];
    const int b = blockIdx.x, t = threadIdx.x;
    int node = (b << BSH) + t;
    if (t < 128) cur[t] = (node < n) ? rowptr[node] : 0;
    __syncthreads();
    int beg = bo[b], end = bo[b + 1];
    for (int i = beg + t; i < end; i += 256) {
        int2 pr = pairs[i];
        int p = atomicAdd(&cur[pr.y & 127], 1);
        csr_src[p] = pr.x;
    }
}

// ---------------- W1 -> fp16 (once) ----------------
__global__ void k_whalf(const float* __restrict__ W1, _Float16* __restrict__ Wh, int total) {
    int i = blockIdx.x * 256 + threadIdx.x;
    if (i < total) Wh[i] = (_Float16)W1[i];
}

// ---------------- GEMM1: W-in-LDS (staged once), barrier-free K-loop, fp16 MFMA ----------------
// Block = 64 M-rows, 4 waves; wave owns 16 rows x all 128 N.
// Output layout is feature-group-blocked: hsg[(g*n + node)*16 + f_in_group], g = col>>4.
__global__ __launch_bounds__(256) void k_gemm(const float* __restrict__ x,
                                              const _Float16* __restrict__ Wh,
                                              const float* __restrict__ dinv,
                                              __half* __restrict__ hsg, int n) {
    __shared__ _Float16 Ws[HID][WPAD];   // 67.6 KB
    const int tid = threadIdx.x;
    const int l   = tid & 63;
    const int w   = tid >> 6;
    const int fr  = l & 15;
    const int kg  = l >> 4;
    const int i0  = blockIdx.x * 64 + w * 16;

    const int r0 = i0 + fr;
    const float* xp = &x[(size_t)(r0 < n ? r0 : 0) * FIN + kg * 8];

    // issue the whole x row-slice up front (16 x dwordx4 in flight)
    float4 xv[8][2];
    #pragma unroll
    for (int ks = 0; ks < 8; ++ks) {
        xv[ks][0] = *(const float4*)&xp[ks * 32];
        xv[ks][1] = *(const float4*)&xp[ks * 32 + 4];
    }

    // cooperative W staging: 4096 chunks of 8 halfs, coalesced global reads
    #pragma unroll
    for (int j = 0; j < 16; ++j) {
        int c    = j * 256 + tid;
        int row  = c >> 5;
        int col8 = c & 31;
        *(half8v*)&Ws[row][col8 * 8] = *(const half8v*)&Wh[row * FIN + col8 * 8];
    }
    __syncthreads();

    f32x4 acc[8] = {};
    #pragma unroll
    for (int ks = 0; ks < 8; ++ks) {
        half8v ha;
        ha[0] = (_Float16)xv[ks][0].x; ha[1] = (_Float16)xv[ks][0].y;
        ha[2] = (_Float16)xv[ks][0].z; ha[3] = (_Float16)xv[ks][0].w;
        ha[4] = (_Float16)xv[ks][1].x; ha[5] = (_Float16)xv[ks][1].y;
        ha[6] = (_Float16)xv[ks][1].z; ha[7] = (_Float16)xv[ks][1].w;
        #pragma unroll
        for (int nt = 0; nt < 8; ++nt) {
            half8v hb = *(const half8v*)&Ws[nt * 16 + fr][kg * 8 + ks * 32];
            acc[nt] = __builtin_amdgcn_mfma_f32_16x16x32_f16(ha, hb, acc[nt], 0, 0, 0);
        }
    }

    // D(m,n): row = kg*4 + reg (M), col = nt*16 + fr (N); group = nt
    int rbase = i0 + kg * 4;
    if (rbase < n) {
        float4 dv = *(const float4*)&dinv[rbase];
        #pragma unroll
        for (int nt = 0; nt < 8; ++nt) {
            f32x4 c = acc[nt];
            #pragma unroll
            for (int r = 0; r < 4; ++r) {
                int gi = rbase + r;
                if (gi < n)
                    hsg[((size_t)nt * n + gi) * 16 + fr] =
                        __float2half(((const float*)&c)[r] * ((const float*)&dv)[r]);
            }
        }
    }
}

// ---------------- layer-1 aggregation, feature-group sliced (XCD-L2-resident) ----------------
// group g = blockIdx.x % 8 rides the gfx950 round-robin XCD dispatch: each XCD's
// gather hits its own 3.2 MB hsg slice in L2. Wave = 1 node: lane = slot(8) x fpair(8).
__global__ __launch_bounds__(256) void k_gagg(const unsigned int* __restrict__ hsg,
                                              const int* __restrict__ rowptr,
                                              const int* __restrict__ csr_src,
                                              const float* __restrict__ dinv,
                                              const float* __restrict__ b1, const float* __restrict__ W2,
                                              float* __restrict__ zg, int n) {
    const int g = blockIdx.x & 7;
    const int i = (blockIdx.x >> 3) * 4 + (threadIdx.x >> 6);
    if (i >= n) return;
    const int lane = threadIdx.x & 63;
    const int per  = lane >> 3;    // edge slot 0..7
    const int fp   = lane & 7;     // feature pair 0..7 (features 2fp, 2fp+1 of group)
    const unsigned int* base = hsg + (size_t)g * n * 8;   // 8 uints (16 halfs) per node

    // self-loop term on slot 0 only (all lanes load; broadcast-served)
    unsigned int sv = base[(size_t)i * 8 + fp];
    float2 sf = __half22float2(*reinterpret_cast<__half2*>(&sv));
    float ax = (per == 0) ? sf.x : 0.f;
    float ay = (per == 0) ? sf.y : 0.f;

    const int beg = rowptr[i], end = rowptr[i + 1];
    for (int t = beg + per; t < end; t += 8) {
        int s = csr_src[t];
        unsigned int v = base[(size_t)s * 8 + fp];
        float2 f = __half22float2(*reinterpret_cast<__half2*>(&v));
        ax += f.x; ay += f.y;
    }
    // reduce across the 8 edge slots (stride-8 lanes share a feature pair)
    ax += __shfl_xor(ax, 8, 64);  ay += __shfl_xor(ay, 8, 64);
    ax += __shfl_xor(ax, 16, 64); ay += __shfl_xor(ay, 16, 64);
    ax += __shfl_xor(ax, 32, 64); ay += __shfl_xor(ay, 32, 64);

    float di = dinv[i];
    float2 bb = ((const float2*)b1)[g * 8 + fp];
    float2 w2 = ((const float2*)W2)[g * 8 + fp];
    float h0 = fmaxf(ax * di + bb.x, 0.f);
    float h1 = fmaxf(ay * di + bb.y, 0.f);
    float z = h0 * w2.x + h1 * w2.y;
    z += __shfl_xor(z, 1, 64);
    z += __shfl_xor(z, 2, 64);
    z += __shfl_xor(z, 4, 64);
    if (lane == 0) zg[(size_t)g * n + i] = z;
}

// ---------------- fold 8 group partials -> zs (pre-scaled by dinv) ----------------
__global__ void k_zsum(const float* __restrict__ zg, const float* __restrict__ dinv,
                       float* __restrict__ zs, int n) {
    int i = blockIdx.x * 256 + threadIdx.x;
    if (i >= n) return;
    float s = 0.f;
    #pragma unroll
    for (int g = 0; g < 8; ++g) s += zg[(size_t)g * n + i];
    zs[i] = s * dinv[i];
}

// ---------------- layer-2 aggregation ----------------
__global__ void k_agg2(const float* __restrict__ zs, const int* __restrict__ rowptr,
                       const int* __restrict__ csr_src, const float* __restrict__ dinv,
                       const float* __restrict__ b2, float* __restrict__ out, int n) {
    int i = blockIdx.x * blockDim.x + threadIdx.x;
    if (i >= n) return;
    float acc = zs[i];
    int beg = rowptr[i], end = rowptr[i + 1];
    for (int e = beg; e < end; ++e) acc += zs[csr_src[e]];
    out[i] = acc * dinv[i] + b2[0];
}

extern "C" void kernel_launch(void* const* d_in, const int* in_sizes, int n_in,
                              void* d_out, int out_size, void* d_ws, size_t ws_size,
                              hipStream_t stream) {
    const float* x  = (const float*)d_in[0];
    const int*   ei = (const int*)d_in[1];
    const float* W1 = (const float*)d_in[2];
    const float* b1 = (const float*)d_in[3];
    const float* W2 = (const float*)d_in[4];
    const float* b2 = (const float*)d_in[5];
    float* out = (float*)d_out;

    const int n = in_sizes[0] / FIN;
    const int e = in_sizes[1] / 2;
    const int* src = ei;
    const int* dst = ei + e;
    const int nbk = (n + (1 << BSH) - 1) >> BSH;

    char* p = (char*)d_ws;
    auto carve = [&](size_t bytes) { char* q = p; p += (bytes + 255) & ~(size_t)255; return q; };
    int*            deg     = (int*)carve((size_t)n * 4);
    int*            bcnt    = (int*)carve((size_t)NBK_MAX * 4);
    int*            partial = (int*)carve((size_t)n * 4);
    int*            bsum    = (int*)carve(4096);
    int*            boff    = (int*)carve(4096);
    int*            bo      = (int*)carve((size_t)(NBK_MAX + 1) * 4);
    int*            bcur    = (int*)carve((size_t)NBK_MAX * 4);
    int*            rowptr  = (int*)carve((size_t)(n + 1) * 4);
    float*          dinv    = (float*)carve((size_t)n * 4);
    int*            csr     = (int*)carve((size_t)e * 4);
    int2*           pairs   = (int2*)carve((size_t)e * 8);
    __half*         hsg     = (__half*)carve((size_t)n * HID * 2);
    float*          zg      = (float*)carve((size_t)n * 8 * 4);
    float*          zs      = (float*)carve((size_t)n * 4);
    _Float16*       Wh      = (_Float16*)carve((size_t)HID * FIN * 2);

    hipMemsetAsync(bcnt, 0, (size_t)NBK_MAX * 4, stream);

    const int nb  = (n + 255) / 256;
    const int neb = (e + EPB - 1) / EPB;
    k_whalf<<<(HID * FIN + 255) / 256, 256, 0, stream>>>(W1, Wh, HID * FIN);
    k_hist <<<neb, 256, 0, stream>>>(dst, bcnt, nbk, e);
    k_bscan<<<1, 1024, 0, stream>>>(bcnt, bo, bcur, nbk, e);
    k_pair2<<<neb, 256, 0, stream>>>(src, dst, bcur, pairs, nbk, e);
    k_bdeg <<<nbk, 256, 0, stream>>>(pairs, bo, deg, n);
    k_scan1<<<nb, 256, 0, stream>>>(deg, partial, bsum, n);
    k_scan2<<<1, 512, 0, stream>>>(bsum, boff, nb);
    k_scan3<<<nb, 256, 0, stream>>>(deg, partial, boff, rowptr, dinv, n, e);
    k_bfill<<<nbk, 256, 0, stream>>>(pairs, bo, rowptr, csr, n);
    k_gemm <<<(n + 63) / 64, 256, 0, stream>>>(x, Wh, dinv, hsg, n);
    k_gagg <<<8 * ((n + 3) / 4), 256, 0, stream>>>((const unsigned int*)hsg, rowptr, csr, dinv, b1, W2, zg, n);
    k_zsum <<<nb, 256, 0, stream>>>(zg, dinv, zs, n);
    k_agg2 <<<(n + 255) / 256, 256, 0, stream>>>(zs, rowptr, csr, dinv, b2, out, n);
}

// Round 13
// 177.305 us; speedup vs baseline: 1.9302x; 1.9302x over previous
//
#include <hip/hip_runtime.h>
#include <hip/hip_bf16.h>
#include <hip/hip_fp16.h>

#define FIN 256
#define HID 128
#define BSH 7            // bucket = dst >> 7 (128 nodes/bucket)
#define NBK_MAX 1024
#define EPB 4096         // edges per block in hist/pair kernels
#define WPAD 264         // 256 + 8 halfs row pad

typedef __attribute__((ext_vector_type(8))) _Float16 half8v;  // f16x8 MFMA frag (4 VGPRs)
typedef __attribute__((ext_vector_type(4))) float f32x4;      // MFMA acc

// ---------------- bucket histogram via LDS ----------------
__global__ __launch_bounds__(256) void k_hist(const int* __restrict__ dst, int* __restrict__ bcnt,
                                              int nbk, int e) {
    __shared__ int cnt[NBK_MAX];
    int t = threadIdx.x;
    for (int b = t; b < nbk; b += 256) cnt[b] = 0;
    __syncthreads();
    int e0 = blockIdx.x * EPB;
    #pragma unroll
    for (int j = 0; j < EPB; j += 256) {
        int idx = e0 + j + t;
        if (idx < e) atomicAdd(&cnt[dst[idx] >> BSH], 1);
    }
    __syncthreads();
    for (int b = t; b < nbk; b += 256)
        if (cnt[b]) atomicAdd(&bcnt[b], cnt[b]);
}

// ---------------- bucket scan (single block) ----------------
__global__ __launch_bounds__(1024) void k_bscan(const int* __restrict__ bcnt, int* __restrict__ bo,
                                                int* __restrict__ bcur, int nbk, int e) {
    __shared__ int sm[1024];
    int t = threadIdx.x;
    int v = (t < nbk) ? bcnt[t] : 0;
    sm[t] = v;
    __syncthreads();
    int acc = v;
    for (int off = 1; off < 1024; off <<= 1) {
        int u = (t >= off) ? sm[t - off] : 0;
        __syncthreads();
        acc += u;
        sm[t] = acc;
        __syncthreads();
    }
    if (t < nbk) { bo[t] = acc - v; bcur[t] = acc - v; }
    if (t == 0) bo[nbk] = e;
}

// ---------------- two-phase pair scatter (LDS counts, 1 global atomic per block-bucket) ----------------
__global__ __launch_bounds__(256) void k_pair2(const int* __restrict__ src, const int* __restrict__ dst,
                                               int* __restrict__ bcur, int2* __restrict__ pairs,
                                               int nbk, int e) {
    __shared__ int cnt[NBK_MAX];
    __shared__ int base[NBK_MAX];
    const int t = threadIdx.x;
    for (int b = t; b < nbk; b += 256) cnt[b] = 0;
    __syncthreads();
    const int e0 = blockIdx.x * EPB;
    int s[16], d[16], lo[16];
    #pragma unroll
    for (int j = 0; j < 16; ++j) {
        int idx = e0 + j * 256 + t;
        if (idx < e) {
            s[j] = src[idx];
            d[j] = dst[idx];
            lo[j] = atomicAdd(&cnt[d[j] >> BSH], 1);
        }
    }
    __syncthreads();
    for (int b = t; b < nbk; b += 256)
        base[b] = cnt[b] ? atomicAdd(&bcur[b], cnt[b]) : 0;
    __syncthreads();
    #pragma unroll
    for (int j = 0; j < 16; ++j) {
        int idx = e0 + j * 256 + t;
        if (idx < e) pairs[base[d[j] >> BSH] + lo[j]] = make_int2(s[j], d[j]);
    }
}

// ---------------- per-bucket degree (LDS histogram, plain stores) ----------------
__global__ __launch_bounds__(256) void k_bdeg(const int2* __restrict__ pairs, const int* __restrict__ bo,
                                              int* __restrict__ deg, int n) {
    __shared__ int cnt[128];
    const int b = blockIdx.x, t = threadIdx.x;
    if (t < 128) cnt[t] = 0;
    __syncthreads();
    int beg = bo[b], end = bo[b + 1];
    for (int i = beg + t; i < end; i += 256) atomicAdd(&cnt[pairs[i].y & 127], 1);
    __syncthreads();
    int node = (b << BSH) + t;
    if (t < 128 && node < n) deg[node] = cnt[t];
}

// ---------------- 3-kernel exclusive scan over deg ----------------
__global__ __launch_bounds__(256) void k_scan1(const int* __restrict__ deg, int* __restrict__ partial,
                                               int* __restrict__ bsum, int n) {
    __shared__ int sm[256];
    int t = threadIdx.x;
    int i = blockIdx.x * 256 + t;
    int v = (i < n) ? deg[i] : 0;
    sm[t] = v;
    __syncthreads();
    int acc = v;
    for (int off = 1; off < 256; off <<= 1) {
        int u = (t >= off) ? sm[t - off] : 0;
        __syncthreads();
        acc += u;
        sm[t] = acc;
        __syncthreads();
    }
    if (i < n) partial[i] = acc;
    if (t == 255) bsum[blockIdx.x] = acc;
}

__global__ __launch_bounds__(512) void k_scan2(const int* __restrict__ bsum, int* __restrict__ boff, int nb) {
    __shared__ int sm[512];
    int t = threadIdx.x;
    int v = (t < nb) ? bsum[t] : 0;
    sm[t] = v;
    __syncthreads();
    int acc = v;
    for (int off = 1; off < 512; off <<= 1) {
        int u = (t >= off) ? sm[t - off] : 0;
        __syncthreads();
        acc += u;
        sm[t] = acc;
        __syncthreads();
    }
    if (t < nb) boff[t] = acc - v;
}

__global__ __launch_bounds__(256) void k_scan3(const int* __restrict__ deg, const int* __restrict__ partial,
                                               const int* __restrict__ boff, int* __restrict__ rowptr,
                                               float* __restrict__ dinv, int n, int e) {
    int i = blockIdx.x * 256 + threadIdx.x;
    if (i >= n) return;
    rowptr[i] = boff[blockIdx.x] + partial[i] - deg[i];
    dinv[i] = rsqrtf((float)(deg[i] + 1));
    if (i == 0) rowptr[n] = e;
}

// ---------------- per-bucket CSR fill (LDS cursors seeded from rowptr) ----------------
__global__ __launch_bounds__(256) void k_bfill(const int2* __restrict__ pairs, const int* __restrict__ bo,
                                               const int* __restrict__ rowptr, int* __restrict__ csr_src,
                                               int n) {
    __shared__ int cur[128];
    const int b = blockIdx.x, t = threadIdx.x;
    int node = (b << BSH) + t;
    if (t < 128) cur[t] = (node < n) ? rowptr[node] : 0;
    __syncthreads();
    int beg = bo[b], end = bo[b + 1];
    for (int i = beg + t; i < end; i += 256) {
        int2 pr = pairs[i];
        int p = atomicAdd(&cur[pr.y & 127], 1);
        csr_src[p] = pr.x;
    }
}

// ---------------- W1 -> fp16 (once) ----------------
__global__ void k_whalf(const float* __restrict__ W1, _Float16* __restrict__ Wh, int total) {
    int i = blockIdx.x * 256 + threadIdx.x;
    if (i < total) Wh[i] = (_Float16)W1[i];
}

// ---------------- GEMM1: W-in-LDS (staged once), barrier-free K-loop, fp16 MFMA ----------------
// Block = 64 M-rows, 4 waves; wave owns 16 rows x all 128 N.
__global__ __launch_bounds__(256) void k_gemm(const float* __restrict__ x,
                                              const _Float16* __restrict__ Wh,
                                              const float* __restrict__ dinv,
                                              __half* __restrict__ hs, int n) {
    __shared__ _Float16 Ws[HID][WPAD];   // 67.6 KB
    const int tid = threadIdx.x;
    const int l   = tid & 63;
    const int w   = tid >> 6;
    const int fr  = l & 15;
    const int kg  = l >> 4;
    const int i0  = blockIdx.x * 64 + w * 16;

    const int r0 = i0 + fr;
    const float* xp = &x[(size_t)(r0 < n ? r0 : 0) * FIN + kg * 8];

    // issue the whole x row-slice up front (16 x dwordx4 in flight)
    float4 xv[8][2];
    #pragma unroll
    for (int ks = 0; ks < 8; ++ks) {
        xv[ks][0] = *(const float4*)&xp[ks * 32];
        xv[ks][1] = *(const float4*)&xp[ks * 32 + 4];
    }

    // cooperative W staging: 4096 chunks of 8 halfs, coalesced global reads
    #pragma unroll
    for (int j = 0; j < 16; ++j) {
        int c    = j * 256 + tid;
        int row  = c >> 5;
        int col8 = c & 31;
        *(half8v*)&Ws[row][col8 * 8] = *(const half8v*)&Wh[row * FIN + col8 * 8];
    }
    __syncthreads();

    f32x4 acc[8] = {};
    #pragma unroll
    for (int ks = 0; ks < 8; ++ks) {
        half8v ha;
        ha[0] = (_Float16)xv[ks][0].x; ha[1] = (_Float16)xv[ks][0].y;
        ha[2] = (_Float16)xv[ks][0].z; ha[3] = (_Float16)xv[ks][0].w;
        ha[4] = (_Float16)xv[ks][1].x; ha[5] = (_Float16)xv[ks][1].y;
        ha[6] = (_Float16)xv[ks][1].z; ha[7] = (_Float16)xv[ks][1].w;
        #pragma unroll
        for (int nt = 0; nt < 8; ++nt) {
            half8v hb = *(const half8v*)&Ws[nt * 16 + fr][kg * 8 + ks * 32];
            acc[nt] = __builtin_amdgcn_mfma_f32_16x16x32_f16(ha, hb, acc[nt], 0, 0, 0);
        }
    }

    // D(m,n): row = kg*4 + reg (M), col = nt*16 + fr (N)
    int rbase = i0 + kg * 4;
    if (rbase < n) {
        float4 dv = *(const float4*)&dinv[rbase];
        #pragma unroll
        for (int nt = 0; nt < 8; ++nt) {
            f32x4 c = acc[nt];
            int col = nt * 16 + fr;
            #pragma unroll
            for (int r = 0; r < 4; ++r) {
                int gi = rbase + r;
                if (gi < n)
                    hs[(size_t)gi * HID + col] = __float2half(((const float*)&c)[r] * ((const float*)&dv)[r]);
            }
        }
    }
}

// ---------------- layer-1 aggregation fused with layer-2 dot ----------------
// one wave per node; hs rows fp16 (lane owns features 2*lane, 2*lane+1).
// 4 gathers in flight (MLP), packed v_pk_add_f16 accumulation (2 alternating accs).
__global__ __launch_bounds__(256) void k_agg1(const unsigned int* __restrict__ hs,
                                              const int* __restrict__ rowptr,
                                              const int* __restrict__ csr_src,
                                              const float* __restrict__ dinv,
                                              const float* __restrict__ b1, const float* __restrict__ W2,
                                              float* __restrict__ zs, int n) {
    int i = (blockIdx.x << 2) + (threadIdx.x >> 6);
    if (i >= n) return;
    const int lane = threadIdx.x & 63;

    unsigned int sv = hs[((size_t)i << 6) + lane];         // self-loop term (fp32)
    float2 sf = __half22float2(*reinterpret_cast<__half2*>(&sv));
    float ax = sf.x, ay = sf.y;

    __half2 acc0 = __float2half2_rn(0.f);
    __half2 acc1 = __float2half2_rn(0.f);

    int e = rowptr[i];
    const int end = rowptr[i + 1];
    while (e < end) {
        int cnt = end - e;
        if (cnt > 64) cnt = 64;
        int sidx = (lane < cnt) ? csr_src[e + lane] : 0;
        int j = 0;
        for (; j + 4 <= cnt; j += 4) {
            int s0 = __shfl(sidx, j, 64);
            int s1 = __shfl(sidx, j + 1, 64);
            int s2 = __shfl(sidx, j + 2, 64);
            int s3 = __shfl(sidx, j + 3, 64);
            unsigned int v0 = hs[((size_t)s0 << 6) + lane];
            unsigned int v1 = hs[((size_t)s1 << 6) + lane];
            unsigned int v2 = hs[((size_t)s2 << 6) + lane];
            unsigned int v3 = hs[((size_t)s3 << 6) + lane];
            acc0 = __hadd2(acc0, *reinterpret_cast<__half2*>(&v0));
            acc1 = __hadd2(acc1, *reinterpret_cast<__half2*>(&v1));
            acc0 = __hadd2(acc0, *reinterpret_cast<__half2*>(&v2));
            acc1 = __hadd2(acc1, *reinterpret_cast<__half2*>(&v3));
        }
        for (; j < cnt; ++j) {
            int s0 = __shfl(sidx, j, 64);
            unsigned int v0 = hs[((size_t)s0 << 6) + lane];
            acc0 = __hadd2(acc0, *reinterpret_cast<__half2*>(&v0));
        }
        e += cnt;
    }
    float2 f0 = __half22float2(acc0);
    float2 f1 = __half22float2(acc1);
    ax += f0.x + f1.x;
    ay += f0.y + f1.y;

    float di = dinv[i];
    float2 bb = ((const float2*)b1)[lane];
    float h0 = fmaxf(ax * di + bb.x, 0.f);
    float h1 = fmaxf(ay * di + bb.y, 0.f);
    float2 w2 = ((const float2*)W2)[lane];
    float z = h0 * w2.x + h1 * w2.y;
    #pragma unroll
    for (int off = 32; off; off >>= 1) z += __shfl_xor(z, off, 64);
    if (lane == 0) zs[i] = z * di;
}

// ---------------- layer-2 aggregation ----------------
__global__ void k_agg2(const float* __restrict__ zs, const int* __restrict__ rowptr,
                       const int* __restrict__ csr_src, const float* __restrict__ dinv,
                       const float* __restrict__ b2, float* __restrict__ out, int n) {
    int i = blockIdx.x * blockDim.x + threadIdx.x;
    if (i >= n) return;
    float acc = zs[i];
    int beg = rowptr[i], end = rowptr[i + 1];
    for (int e = beg; e < end; ++e) acc += zs[csr_src[e]];
    out[i] = acc * dinv[i] + b2[0];
}

extern "C" void kernel_launch(void* const* d_in, const int* in_sizes, int n_in,
                              void* d_out, int out_size, void* d_ws, size_t ws_size,
                              hipStream_t stream) {
    const float* x  = (const float*)d_in[0];
    const int*   ei = (const int*)d_in[1];
    const float* W1 = (const float*)d_in[2];
    const float* b1 = (const float*)d_in[3];
    const float* W2 = (const float*)d_in[4];
    const float* b2 = (const float*)d_in[5];
    float* out = (float*)d_out;

    const int n = in_sizes[0] / FIN;
    const int e = in_sizes[1] / 2;
    const int* src = ei;
    const int* dst = ei + e;
    const int nbk = (n + (1 << BSH) - 1) >> BSH;

    char* p = (char*)d_ws;
    auto carve = [&](size_t bytes) { char* q = p; p += (bytes + 255) & ~(size_t)255; return q; };
    int*            deg     = (int*)carve((size_t)n * 4);
    int*            bcnt    = (int*)carve((size_t)NBK_MAX * 4);
    int*            partial = (int*)carve((size_t)n * 4);
    int*            bsum    = (int*)carve(4096);
    int*            boff    = (int*)carve(4096);
    int*            bo      = (int*)carve((size_t)(NBK_MAX + 1) * 4);
    int*            bcur    = (int*)carve((size_t)NBK_MAX * 4);
    int*            rowptr  = (int*)carve((size_t)(n + 1) * 4);
    float*          dinv    = (float*)carve((size_t)n * 4);
    int*            csr     = (int*)carve((size_t)e * 4);
    int2*           pairs   = (int2*)carve((size_t)e * 8);
    __half*         hs      = (__half*)carve((size_t)n * HID * 2);
    float*          zs      = (float*)carve((size_t)n * 4);
    _Float16*       Wh      = (_Float16*)carve((size_t)HID * FIN * 2);

    hipMemsetAsync(bcnt, 0, (size_t)NBK_MAX * 4, stream);

    const int nb  = (n + 255) / 256;
    const int neb = (e + EPB - 1) / EPB;
    k_whalf<<<(HID * FIN + 255) / 256, 256, 0, stream>>>(W1, Wh, HID * FIN);
    k_hist <<<neb, 256, 0, stream>>>(dst, bcnt, nbk, e);
    k_bscan<<<1, 1024, 0, stream>>>(bcnt, bo, bcur, nbk, e);
    k_pair2<<<neb, 256, 0, stream>>>(src, dst, bcur, pairs, nbk, e);
    k_bdeg <<<nbk, 256, 0, stream>>>(pairs, bo, deg, n);
    k_scan1<<<nb, 256, 0, stream>>>(deg, partial, bsum, n);
    k_scan2<<<1, 512, 0, stream>>>(bsum, boff, nb);
    k_scan3<<<nb, 256, 0, stream>>>(deg, partial, boff, rowptr, dinv, n, e);
    k_bfill<<<nbk, 256, 0, stream>>>(pairs, bo, rowptr, csr, n);
    k_gemm <<<(n + 63) / 64, 256, 0, stream>>>(x, Wh, dinv, hs, n);
    k_agg1 <<<(n + 3) / 4, 256, 0, stream>>>((const unsigned int*)hs, rowptr, csr, dinv, b1, W2, zs, n);
    k_agg2 <<<(n + 255) / 256, 256, 0, stream>>>(zs, rowptr, csr, dinv, b2, out, n);
}

// Round 14
// 164.076 us; speedup vs baseline: 2.0858x; 1.0806x over previous
//
#include <hip/hip_runtime.h>
#include <hip/hip_bf16.h>
#include <hip/hip_fp16.h>

#define FIN 256
#define HID 128
#define BSH 7            // bucket = dst >> 7 (128 nodes/bucket)
#define NBK_MAX 1024
#define EPB 4096         // edges per block in hist/pair kernels
#define WPAD 264         // 256 + 8 halfs row pad

typedef __attribute__((ext_vector_type(8))) _Float16 half8v;  // f16x8 MFMA frag (4 VGPRs)
typedef __attribute__((ext_vector_type(4))) float f32x4;      // MFMA acc

// ---------------- bucket histogram via LDS ----------------
__global__ __launch_bounds__(256) void k_hist(const int* __restrict__ dst, int* __restrict__ bcnt,
                                              int nbk, int e) {
    __shared__ int cnt[NBK_MAX];
    int t = threadIdx.x;
    for (int b = t; b < nbk; b += 256) cnt[b] = 0;
    __syncthreads();
    int e0 = blockIdx.x * EPB;
    #pragma unroll
    for (int j = 0; j < EPB; j += 256) {
        int idx = e0 + j + t;
        if (idx < e) atomicAdd(&cnt[dst[idx] >> BSH], 1);
    }
    __syncthreads();
    for (int b = t; b < nbk; b += 256)
        if (cnt[b]) atomicAdd(&bcnt[b], cnt[b]);
}

// ---------------- bucket scan (single block) ----------------
__global__ __launch_bounds__(1024) void k_bscan(const int* __restrict__ bcnt, int* __restrict__ bo,
                                                int* __restrict__ bcur, int nbk, int e) {
    __shared__ int sm[1024];
    int t = threadIdx.x;
    int v = (t < nbk) ? bcnt[t] : 0;
    sm[t] = v;
    __syncthreads();
    int acc = v;
    for (int off = 1; off < 1024; off <<= 1) {
        int u = (t >= off) ? sm[t - off] : 0;
        __syncthreads();
        acc += u;
        sm[t] = acc;
        __syncthreads();
    }
    if (t < nbk) { bo[t] = acc - v; bcur[t] = acc - v; }
    if (t == 0) bo[nbk] = e;
}

// ---------------- two-phase pair scatter, packed (src<<7 | dst&127) ----------------
__global__ __launch_bounds__(256) void k_pair2(const int* __restrict__ src, const int* __restrict__ dst,
                                               int* __restrict__ bcur, unsigned int* __restrict__ pairs,
                                               int nbk, int e) {
    __shared__ int cnt[NBK_MAX];
    __shared__ int base[NBK_MAX];
    const int t = threadIdx.x;
    for (int b = t; b < nbk; b += 256) cnt[b] = 0;
    __syncthreads();
    const int e0 = blockIdx.x * EPB;
    int s[16], d[16], lo[16];
    #pragma unroll
    for (int j = 0; j < 16; ++j) {
        int idx = e0 + j * 256 + t;
        if (idx < e) {
            s[j] = src[idx];
            d[j] = dst[idx];
            lo[j] = atomicAdd(&cnt[d[j] >> BSH], 1);
        }
    }
    __syncthreads();
    for (int b = t; b < nbk; b += 256)
        base[b] = cnt[b] ? atomicAdd(&bcur[b], cnt[b]) : 0;
    __syncthreads();
    #pragma unroll
    for (int j = 0; j < 16; ++j) {
        int idx = e0 + j * 256 + t;
        if (idx < e)
            pairs[base[d[j] >> BSH] + lo[j]] = ((unsigned int)s[j] << 7) | (unsigned int)(d[j] & 127);
    }
}

// ---------------- fused CSR build: per-bucket histogram + scan + fill + rowptr + dinv ----------------
__global__ __launch_bounds__(256) void k_csr(const unsigned int* __restrict__ pairs,
                                             const int* __restrict__ bo,
                                             int* __restrict__ rowptr, float* __restrict__ dinv,
                                             int* __restrict__ csr_src, int n, int e) {
    __shared__ int cnt[128];
    __shared__ int cur[128];
    const int b = blockIdx.x, t = threadIdx.x;
    if (t < 128) cnt[t] = 0;
    __syncthreads();
    const int beg = bo[b], end = bo[b + 1];
    for (int i = beg + t; i < end; i += 256)
        atomicAdd(&cnt[pairs[i] & 127], 1);
    __syncthreads();
    if (t < 128) cur[t] = cnt[t];
    __syncthreads();
    // Hillis-Steele inclusive scan over 128 counters
    for (int off = 1; off < 128; off <<= 1) {
        int u = (t < 128 && t >= off) ? cur[t - off] : 0;
        __syncthreads();
        if (t < 128) cur[t] += u;
        __syncthreads();
    }
    int myexcl = 0;
    const int node = (b << BSH) + t;
    if (t < 128) {
        myexcl = beg + cur[t] - cnt[t];
        if (node < n) {
            rowptr[node] = myexcl;
            dinv[node] = rsqrtf((float)(cnt[t] + 1));   // +1 self loop
        }
    }
    if (b == (int)gridDim.x - 1 && t == 0) rowptr[n] = e;
    __syncthreads();
    if (t < 128) cur[t] = myexcl;
    __syncthreads();
    for (int i = beg + t; i < end; i += 256) {
        unsigned int pr = pairs[i];
        int p = atomicAdd(&cur[pr & 127], 1);
        csr_src[p] = (int)(pr >> 7);
    }
}

// ---------------- W1 -> fp16 (once) ----------------
__global__ void k_whalf(const float* __restrict__ W1, _Float16* __restrict__ Wh, int total) {
    int i = blockIdx.x * 256 + threadIdx.x;
    if (i < total) Wh[i] = (_Float16)W1[i];
}

// ---------------- GEMM1: W-in-LDS (staged once), barrier-free K-loop, fp16 MFMA ----------------
__global__ __launch_bounds__(256) void k_gemm(const float* __restrict__ x,
                                              const _Float16* __restrict__ Wh,
                                              const float* __restrict__ dinv,
                                              __half* __restrict__ hs, int n) {
    __shared__ _Float16 Ws[HID][WPAD];   // 67.6 KB
    const int tid = threadIdx.x;
    const int l   = tid & 63;
    const int w   = tid >> 6;
    const int fr  = l & 15;
    const int kg  = l >> 4;
    const int i0  = blockIdx.x * 64 + w * 16;

    const int r0 = i0 + fr;
    const float* xp = &x[(size_t)(r0 < n ? r0 : 0) * FIN + kg * 8];

    float4 xv[8][2];
    #pragma unroll
    for (int ks = 0; ks < 8; ++ks) {
        xv[ks][0] = *(const float4*)&xp[ks * 32];
        xv[ks][1] = *(const float4*)&xp[ks * 32 + 4];
    }

    #pragma unroll
    for (int j = 0; j < 16; ++j) {
        int c    = j * 256 + tid;
        int row  = c >> 5;
        int col8 = c & 31;
        *(half8v*)&Ws[row][col8 * 8] = *(const half8v*)&Wh[row * FIN + col8 * 8];
    }
    __syncthreads();

    f32x4 acc[8] = {};
    #pragma unroll
    for (int ks = 0; ks < 8; ++ks) {
        half8v ha;
        ha[0] = (_Float16)xv[ks][0].x; ha[1] = (_Float16)xv[ks][0].y;
        ha[2] = (_Float16)xv[ks][0].z; ha[3] = (_Float16)xv[ks][0].w;
        ha[4] = (_Float16)xv[ks][1].x; ha[5] = (_Float16)xv[ks][1].y;
        ha[6] = (_Float16)xv[ks][1].z; ha[7] = (_Float16)xv[ks][1].w;
        #pragma unroll
        for (int nt = 0; nt < 8; ++nt) {
            half8v hb = *(const half8v*)&Ws[nt * 16 + fr][kg * 8 + ks * 32];
            acc[nt] = __builtin_amdgcn_mfma_f32_16x16x32_f16(ha, hb, acc[nt], 0, 0, 0);
        }
    }

    int rbase = i0 + kg * 4;
    if (rbase < n) {
        float4 dv = *(const float4*)&dinv[rbase];
        #pragma unroll
        for (int nt = 0; nt < 8; ++nt) {
            f32x4 c = acc[nt];
            int col = nt * 16 + fr;
            #pragma unroll
            for (int r = 0; r < 4; ++r) {
                int gi = rbase + r;
                if (gi < n)
                    hs[(size_t)gi * HID + col] = __float2half(((const float*)&c)[r] * ((const float*)&dv)[r]);
            }
        }
    }
}

// ---------------- layer-1 aggregation fused with layer-2 dot ----------------
// one wave per node; SCALARIZED edge stream: node id forced to SGPR so rowptr /
// csr_src go through s_load (scalar pipe) and gathers use SGPR-base addressing.
// Per edge: ~1 VALU (v_pk_add_f16) + 1 VMEM. 8 gathers in flight.
__global__ __launch_bounds__(256) void k_agg1(const unsigned int* __restrict__ hs,
                                              const int* __restrict__ rowptr,
                                              const int* __restrict__ csr_src,
                                              const float* __restrict__ dinv,
                                              const float* __restrict__ b1, const float* __restrict__ W2,
                                              float* __restrict__ zs, int n) {
    const int i = __builtin_amdgcn_readfirstlane((blockIdx.x << 2) + (threadIdx.x >> 6));
    if (i >= n) return;
    const int lane = threadIdx.x & 63;

    unsigned int sv = hs[((size_t)i << 6) + lane];         // self-loop term
    float2 sf = __half22float2(*reinterpret_cast<__half2*>(&sv));
    float ax = sf.x, ay = sf.y;

    __half2 acc0 = __float2half2_rn(0.f);
    __half2 acc1 = __float2half2_rn(0.f);

    const int beg = rowptr[i];
    const int end = rowptr[i + 1];
    int j = beg;
    for (; j + 8 <= end; j += 8) {
        unsigned int v[8];
        #pragma unroll
        for (int k = 0; k < 8; ++k) {
            int s = csr_src[j + k];                        // uniform -> s_load
            v[k] = hs[((size_t)s << 6) + lane];            // SGPR base + lane offset
        }
        #pragma unroll
        for (int k = 0; k < 8; ++k) {
            __half2 hv = *reinterpret_cast<__half2*>(&v[k]);
            if (k & 1) acc1 = __hadd2(acc1, hv);
            else       acc0 = __hadd2(acc0, hv);
        }
    }
    for (; j < end; ++j) {
        int s = csr_src[j];
        unsigned int v = hs[((size_t)s << 6) + lane];
        acc0 = __hadd2(acc0, *reinterpret_cast<__half2*>(&v));
    }

    float2 f0 = __half22float2(acc0);
    float2 f1 = __half22float2(acc1);
    ax += f0.x + f1.x;
    ay += f0.y + f1.y;

    float di = dinv[i];
    float2 bb = ((const float2*)b1)[lane];
    float h0 = fmaxf(ax * di + bb.x, 0.f);
    float h1 = fmaxf(ay * di + bb.y, 0.f);
    float2 w2 = ((const float2*)W2)[lane];
    float z = h0 * w2.x + h1 * w2.y;
    #pragma unroll
    for (int off = 32; off; off >>= 1) z += __shfl_xor(z, off, 64);
    if (lane == 0) zs[i] = z * di;
}

// ---------------- layer-2 aggregation ----------------
__global__ void k_agg2(const float* __restrict__ zs, const int* __restrict__ rowptr,
                       const int* __restrict__ csr_src, const float* __restrict__ dinv,
                       const float* __restrict__ b2, float* __restrict__ out, int n) {
    int i = blockIdx.x * blockDim.x + threadIdx.x;
    if (i >= n) return;
    float acc = zs[i];
    int beg = rowptr[i], end = rowptr[i + 1];
    for (int e = beg; e < end; ++e) acc += zs[csr_src[e]];
    out[i] = acc * dinv[i] + b2[0];
}

extern "C" void kernel_launch(void* const* d_in, const int* in_sizes, int n_in,
                              void* d_out, int out_size, void* d_ws, size_t ws_size,
                              hipStream_t stream) {
    const float* x  = (const float*)d_in[0];
    const int*   ei = (const int*)d_in[1];
    const float* W1 = (const float*)d_in[2];
    const float* b1 = (const float*)d_in[3];
    const float* W2 = (const float*)d_in[4];
    const float* b2 = (const float*)d_in[5];
    float* out = (float*)d_out;

    const int n = in_sizes[0] / FIN;
    const int e = in_sizes[1] / 2;
    const int* src = ei;
    const int* dst = ei + e;
    const int nbk = (n + (1 << BSH) - 1) >> BSH;

    char* p = (char*)d_ws;
    auto carve = [&](size_t bytes) { char* q = p; p += (bytes + 255) & ~(size_t)255; return q; };
    int*            bcnt    = (int*)carve((size_t)NBK_MAX * 4);
    int*            bo      = (int*)carve((size_t)(NBK_MAX + 1) * 4);
    int*            bcur    = (int*)carve((size_t)NBK_MAX * 4);
    int*            rowptr  = (int*)carve((size_t)(n + 1) * 4);
    float*          dinv    = (float*)carve((size_t)n * 4);
    int*            csr     = (int*)carve((size_t)e * 4);
    unsigned int*   pairs   = (unsigned int*)carve((size_t)e * 4);
    __half*         hs      = (__half*)carve((size_t)n * HID * 2);
    float*          zs      = (float*)carve((size_t)n * 4);
    _Float16*       Wh      = (_Float16*)carve((size_t)HID * FIN * 2);

    hipMemsetAsync(bcnt, 0, (size_t)NBK_MAX * 4, stream);

    const int neb = (e + EPB - 1) / EPB;
    k_whalf<<<(HID * FIN + 255) / 256, 256, 0, stream>>>(W1, Wh, HID * FIN);
    k_hist <<<neb, 256, 0, stream>>>(dst, bcnt, nbk, e);
    k_bscan<<<1, 1024, 0, stream>>>(bcnt, bo, bcur, nbk, e);
    k_pair2<<<neb, 256, 0, stream>>>(src, dst, bcur, pairs, nbk, e);
    k_csr  <<<nbk, 256, 0, stream>>>(pairs, bo, rowptr, dinv, csr, n, e);
    k_gemm <<<(n + 63) / 64, 256, 0, stream>>>(x, Wh, dinv, hs, n);
    k_agg1 <<<(n + 3) / 4, 256, 0, stream>>>((const unsigned int*)hs, rowptr, csr, dinv, b1, W2, zs, n);
    k_agg2 <<<(n + 255) / 256, 256, 0, stream>>>(zs, rowptr, csr, dinv, b2, out, n);
}

// Round 15
// 162.173 us; speedup vs baseline: 2.1103x; 1.0117x over previous
//
#include <hip/hip_runtime.h>
#include <hip/hip_bf16.h>
#include <hip/hip_fp16.h>

#define FIN 256
#define HID 128
#define BSH 7            // bucket = dst >> 7 (128 nodes/bucket)
#define NBK_MAX 1024
#define EPB 4096         // edges per block in hist/pair kernels
#define WPAD 264         // 256 + 8 halfs row pad

typedef __attribute__((ext_vector_type(8))) _Float16 half8v;  // f16x8 MFMA frag (4 VGPRs)
typedef __attribute__((ext_vector_type(4))) float f32x4;      // MFMA acc

// ---------------- bucket histogram via LDS ----------------
__global__ __launch_bounds__(256) void k_hist(const int* __restrict__ dst, int* __restrict__ bcnt,
                                              int nbk, int e) {
    __shared__ int cnt[NBK_MAX];
    int t = threadIdx.x;
    for (int b = t; b < nbk; b += 256) cnt[b] = 0;
    __syncthreads();
    int e0 = blockIdx.x * EPB;
    #pragma unroll
    for (int j = 0; j < EPB; j += 256) {
        int idx = e0 + j + t;
        if (idx < e) atomicAdd(&cnt[dst[idx] >> BSH], 1);
    }
    __syncthreads();
    for (int b = t; b < nbk; b += 256)
        if (cnt[b]) atomicAdd(&bcnt[b], cnt[b]);
}

// ---------------- bucket scan (single block) ----------------
__global__ __launch_bounds__(1024) void k_bscan(const int* __restrict__ bcnt, int* __restrict__ bo,
                                                int* __restrict__ bcur, int nbk, int e) {
    __shared__ int sm[1024];
    int t = threadIdx.x;
    int v = (t < nbk) ? bcnt[t] : 0;
    sm[t] = v;
    __syncthreads();
    int acc = v;
    for (int off = 1; off < 1024; off <<= 1) {
        int u = (t >= off) ? sm[t - off] : 0;
        __syncthreads();
        acc += u;
        sm[t] = acc;
        __syncthreads();
    }
    if (t < nbk) { bo[t] = acc - v; bcur[t] = acc - v; }
    if (t == 0) bo[nbk] = e;
}

// ---------------- two-phase pair scatter, packed (src<<7 | dst&127) ----------------
__global__ __launch_bounds__(256) void k_pair2(const int* __restrict__ src, const int* __restrict__ dst,
                                               int* __restrict__ bcur, unsigned int* __restrict__ pairs,
                                               int nbk, int e) {
    __shared__ int cnt[NBK_MAX];
    __shared__ int base[NBK_MAX];
    const int t = threadIdx.x;
    for (int b = t; b < nbk; b += 256) cnt[b] = 0;
    __syncthreads();
    const int e0 = blockIdx.x * EPB;
    int s[16], d[16], lo[16];
    #pragma unroll
    for (int j = 0; j < 16; ++j) {
        int idx = e0 + j * 256 + t;
        if (idx < e) {
            s[j] = src[idx];
            d[j] = dst[idx];
            lo[j] = atomicAdd(&cnt[d[j] >> BSH], 1);
        }
    }
    __syncthreads();
    for (int b = t; b < nbk; b += 256)
        base[b] = cnt[b] ? atomicAdd(&bcur[b], cnt[b]) : 0;
    __syncthreads();
    #pragma unroll
    for (int j = 0; j < 16; ++j) {
        int idx = e0 + j * 256 + t;
        if (idx < e)
            pairs[base[d[j] >> BSH] + lo[j]] = ((unsigned int)s[j] << 7) | (unsigned int)(d[j] & 127);
    }
}

// ---------------- fused CSR build: per-bucket histogram + scan + fill + rowptr + dinv ----------------
__global__ __launch_bounds__(256) void k_csr(const unsigned int* __restrict__ pairs,
                                             const int* __restrict__ bo,
                                             int* __restrict__ rowptr, float* __restrict__ dinv,
                                             int* __restrict__ csr_src, int n, int e) {
    __shared__ int cnt[128];
    __shared__ int cur[128];
    const int b = blockIdx.x, t = threadIdx.x;
    if (t < 128) cnt[t] = 0;
    __syncthreads();
    const int beg = bo[b], end = bo[b + 1];
    for (int i = beg + t; i < end; i += 256)
        atomicAdd(&cnt[pairs[i] & 127], 1);
    __syncthreads();
    if (t < 128) cur[t] = cnt[t];
    __syncthreads();
    // Hillis-Steele inclusive scan over 128 counters
    for (int off = 1; off < 128; off <<= 1) {
        int u = (t < 128 && t >= off) ? cur[t - off] : 0;
        __syncthreads();
        if (t < 128) cur[t] += u;
        __syncthreads();
    }
    int myexcl = 0;
    const int node = (b << BSH) + t;
    if (t < 128) {
        myexcl = beg + cur[t] - cnt[t];
        if (node < n) {
            rowptr[node] = myexcl;
            dinv[node] = rsqrtf((float)(cnt[t] + 1));   // +1 self loop
        }
    }
    if (b == (int)gridDim.x - 1 && t == 0) rowptr[n] = e;
    __syncthreads();
    if (t < 128) cur[t] = myexcl;
    __syncthreads();
    for (int i = beg + t; i < end; i += 256) {
        unsigned int pr = pairs[i];
        int p = atomicAdd(&cur[pr & 127], 1);
        csr_src[p] = (int)(pr >> 7);
    }
}

// ---------------- W1 -> fp16 (once) + bcnt zeroing (replaces hipMemsetAsync) ----------------
__global__ void k_whalf(const float* __restrict__ W1, _Float16* __restrict__ Wh,
                        int* __restrict__ bcnt, int total) {
    int i = blockIdx.x * 256 + threadIdx.x;
    if (i < total) Wh[i] = (_Float16)W1[i];
    if (blockIdx.x == 0) {
        #pragma unroll
        for (int j = 0; j < NBK_MAX; j += 256) bcnt[j + threadIdx.x] = 0;
    }
}

// ---------------- GEMM1: W-in-LDS (staged once), barrier-free K-loop, fp16 MFMA ----------------
// Block = 128 M-rows, 8 waves (512 thr); wave owns 16 rows x all 128 N.
// 2 blocks/CU (135KB LDS) -> 16 waves/CU; launch_bounds caps VGPR at 128.
__global__ __launch_bounds__(512, 4) void k_gemm(const float* __restrict__ x,
                                                 const _Float16* __restrict__ Wh,
                                                 const float* __restrict__ dinv,
                                                 __half* __restrict__ hs, int n) {
    __shared__ _Float16 Ws[HID][WPAD];   // 67.6 KB
    const int tid = threadIdx.x;
    const int l   = tid & 63;
    const int w   = tid >> 6;            // 0..7
    const int fr  = l & 15;
    const int kg  = l >> 4;
    const int i0  = blockIdx.x * 128 + w * 16;

    const int r0 = i0 + fr;
    const float* xp = &x[(size_t)(r0 < n ? r0 : 0) * FIN + kg * 8];

    // issue the whole x row-slice up front (16 x dwordx4 in flight)
    float4 xv[8][2];
    #pragma unroll
    for (int ks = 0; ks < 8; ++ks) {
        xv[ks][0] = *(const float4*)&xp[ks * 32];
        xv[ks][1] = *(const float4*)&xp[ks * 32 + 4];
    }

    // cooperative W staging: 4096 chunks of 8 halfs, coalesced global reads
    #pragma unroll
    for (int j = 0; j < 8; ++j) {
        int c    = j * 512 + tid;
        int row  = c >> 5;
        int col8 = c & 31;
        *(half8v*)&Ws[row][col8 * 8] = *(const half8v*)&Wh[row * FIN + col8 * 8];
    }
    __syncthreads();

    f32x4 acc[8] = {};
    #pragma unroll
    for (int ks = 0; ks < 8; ++ks) {
        half8v ha;
        ha[0] = (_Float16)xv[ks][0].x; ha[1] = (_Float16)xv[ks][0].y;
        ha[2] = (_Float16)xv[ks][0].z; ha[3] = (_Float16)xv[ks][0].w;
        ha[4] = (_Float16)xv[ks][1].x; ha[5] = (_Float16)xv[ks][1].y;
        ha[6] = (_Float16)xv[ks][1].z; ha[7] = (_Float16)xv[ks][1].w;
        #pragma unroll
        for (int nt = 0; nt < 8; ++nt) {
            half8v hb = *(const half8v*)&Ws[nt * 16 + fr][kg * 8 + ks * 32];
            acc[nt] = __builtin_amdgcn_mfma_f32_16x16x32_f16(ha, hb, acc[nt], 0, 0, 0);
        }
    }

    // D(m,n): row = kg*4 + reg (M), col = nt*16 + fr (N)
    int rbase = i0 + kg * 4;
    if (rbase < n) {
        float4 dv = *(const float4*)&dinv[rbase];
        #pragma unroll
        for (int nt = 0; nt < 8; ++nt) {
            f32x4 c = acc[nt];
            int col = nt * 16 + fr;
            #pragma unroll
            for (int r = 0; r < 4; ++r) {
                int gi = rbase + r;
                if (gi < n)
                    hs[(size_t)gi * HID + col] = __float2half(((const float*)&c)[r] * ((const float*)&dv)[r]);
            }
        }
    }
}

// ---------------- layer-1 aggregation fused with layer-2 dot ----------------
// one wave per node; scalarized edge stream (SGPR node id, s_load csr, SGPR-base gathers).
__global__ __launch_bounds__(256) void k_agg1(const unsigned int* __restrict__ hs,
                                              const int* __restrict__ rowptr,
                                              const int* __restrict__ csr_src,
                                              const float* __restrict__ dinv,
                                              const float* __restrict__ b1, const float* __restrict__ W2,
                                              float* __restrict__ zs, int n) {
    const int i = __builtin_amdgcn_readfirstlane((blockIdx.x << 2) + (threadIdx.x >> 6));
    if (i >= n) return;
    const int lane = threadIdx.x & 63;

    unsigned int sv = hs[((size_t)i << 6) + lane];         // self-loop term
    float2 sf = __half22float2(*reinterpret_cast<__half2*>(&sv));
    float ax = sf.x, ay = sf.y;

    __half2 acc0 = __float2half2_rn(0.f);
    __half2 acc1 = __float2half2_rn(0.f);

    const int beg = rowptr[i];
    const int end = rowptr[i + 1];
    int j = beg;
    for (; j + 8 <= end; j += 8) {
        unsigned int v[8];
        #pragma unroll
        for (int k = 0; k < 8; ++k) {
            int s = csr_src[j + k];                        // uniform -> s_load
            v[k] = hs[((size_t)s << 6) + lane];            // SGPR base + lane offset
        }
        #pragma unroll
        for (int k = 0; k < 8; ++k) {
            __half2 hv = *reinterpret_cast<__half2*>(&v[k]);
            if (k & 1) acc1 = __hadd2(acc1, hv);
            else       acc0 = __hadd2(acc0, hv);
        }
    }
    for (; j < end; ++j) {
        int s = csr_src[j];
        unsigned int v = hs[((size_t)s << 6) + lane];
        acc0 = __hadd2(acc0, *reinterpret_cast<__half2*>(&v));
    }

    float2 f0 = __half22float2(acc0);
    float2 f1 = __half22float2(acc1);
    ax += f0.x + f1.x;
    ay += f0.y + f1.y;

    float di = dinv[i];
    float2 bb = ((const float2*)b1)[lane];
    float h0 = fmaxf(ax * di + bb.x, 0.f);
    float h1 = fmaxf(ay * di + bb.y, 0.f);
    float2 w2 = ((const float2*)W2)[lane];
    float z = h0 * w2.x + h1 * w2.y;
    #pragma unroll
    for (int off = 32; off; off >>= 1) z += __shfl_xor(z, off, 64);
    if (lane == 0) zs[i] = z * di;
}

// ---------------- layer-2 aggregation ----------------
__global__ void k_agg2(const float* __restrict__ zs, const int* __restrict__ rowptr,
                       const int* __restrict__ csr_src, const float* __restrict__ dinv,
                       const float* __restrict__ b2, float* __restrict__ out, int n) {
    int i = blockIdx.x * blockDim.x + threadIdx.x;
    if (i >= n) return;
    float acc = zs[i];
    int beg = rowptr[i], end = rowptr[i + 1];
    for (int e = beg; e < end; ++e) acc += zs[csr_src[e]];
    out[i] = acc * dinv[i] + b2[0];
}

extern "C" void kernel_launch(void* const* d_in, const int* in_sizes, int n_in,
                              void* d_out, int out_size, void* d_ws, size_t ws_size,
                              hipStream_t stream) {
    const float* x  = (const float*)d_in[0];
    const int*   ei = (const int*)d_in[1];
    const float* W1 = (const float*)d_in[2];
    const float* b1 = (const float*)d_in[3];
    const float* W2 = (const float*)d_in[4];
    const float* b2 = (const float*)d_in[5];
    float* out = (float*)d_out;

    const int n = in_sizes[0] / FIN;
    const int e = in_sizes[1] / 2;
    const int* src = ei;
    const int* dst = ei + e;
    const int nbk = (n + (1 << BSH) - 1) >> BSH;

    char* p = (char*)d_ws;
    auto carve = [&](size_t bytes) { char* q = p; p += (bytes + 255) & ~(size_t)255; return q; };
    int*            bcnt    = (int*)carve((size_t)NBK_MAX * 4);
    int*            bo      = (int*)carve((size_t)(NBK_MAX + 1) * 4);
    int*            bcur    = (int*)carve((size_t)NBK_MAX * 4);
    int*            rowptr  = (int*)carve((size_t)(n + 1) * 4);
    float*          dinv    = (float*)carve((size_t)n * 4);
    int*            csr     = (int*)carve((size_t)e * 4);
    unsigned int*   pairs   = (unsigned int*)carve((size_t)e * 4);
    __half*         hs      = (__half*)carve((size_t)n * HID * 2);
    float*          zs      = (float*)carve((size_t)n * 4);
    _Float16*       Wh      = (_Float16*)carve((size_t)HID * FIN * 2);

    const int neb = (e + EPB - 1) / EPB;
    k_whalf<<<(HID * FIN + 255) / 256, 256, 0, stream>>>(W1, Wh, bcnt, HID * FIN);
    k_hist <<<neb, 256, 0, stream>>>(dst, bcnt, nbk, e);
    k_bscan<<<1, 1024, 0, stream>>>(bcnt, bo, bcur, nbk, e);
    k_pair2<<<neb, 256, 0, stream>>>(src, dst, bcur, pairs, nbk, e);
    k_csr  <<<nbk, 256, 0, stream>>>(pairs, bo, rowptr, dinv, csr, n, e);
    k_gemm <<<(n + 127) / 128, 512, 0, stream>>>(x, Wh, dinv, hs, n);
    k_agg1 <<<(n + 3) / 4, 256, 0, stream>>>((const unsigned int*)hs, rowptr, csr, dinv, b1, W2, zs, n);
    k_agg2 <<<(n + 255) / 256, 256, 0, stream>>>(zs, rowptr, csr, dinv, b2, out, n);
}

// Round 16
// 158.647 us; speedup vs baseline: 2.1572x; 1.0222x over previous
//
#include <hip/hip_runtime.h>
#include <hip/hip_bf16.h>
#include <hip/hip_fp16.h>

#define FIN 256
#define HID 128
#define BSH 7            // bucket = dst >> 7 (128 nodes/bucket)
#define NBK_MAX 1024
#define EPB 4096         // edges per block in hist/pair kernels
#define WPAD 264         // 256 + 8 halfs row pad

typedef __attribute__((ext_vector_type(8))) _Float16 half8v;  // f16x8 MFMA frag (4 VGPRs)
typedef __attribute__((ext_vector_type(4))) float f32x4;      // MFMA acc

// ---------------- W1 -> fp16 (once) + bcnt zeroing ----------------
__global__ void k_whalf(const float* __restrict__ W1, _Float16* __restrict__ Wh,
                        int* __restrict__ bcnt, int total) {
    int i = blockIdx.x * 256 + threadIdx.x;
    if (i < total) Wh[i] = (_Float16)W1[i];
    if (blockIdx.x == 0) {
        #pragma unroll
        for (int j = 0; j < NBK_MAX; j += 256) bcnt[j + threadIdx.x] = 0;
    }
}

// ---------------- bucket histogram via LDS ----------------
__global__ __launch_bounds__(256) void k_hist(const int* __restrict__ dst, int* __restrict__ bcnt,
                                              int nbk, int e) {
    __shared__ int cnt[NBK_MAX];
    int t = threadIdx.x;
    for (int b = t; b < nbk; b += 256) cnt[b] = 0;
    __syncthreads();
    int e0 = blockIdx.x * EPB;
    #pragma unroll
    for (int j = 0; j < EPB; j += 256) {
        int idx = e0 + j + t;
        if (idx < e) atomicAdd(&cnt[dst[idx] >> BSH], 1);
    }
    __syncthreads();
    for (int b = t; b < nbk; b += 256)
        if (cnt[b]) atomicAdd(&bcnt[b], cnt[b]);
}

// ---------------- bucket scan (single block) ----------------
__global__ __launch_bounds__(1024) void k_bscan(const int* __restrict__ bcnt, int* __restrict__ bo,
                                                int* __restrict__ bcur, int nbk, int e) {
    __shared__ int sm[1024];
    int t = threadIdx.x;
    int v = (t < nbk) ? bcnt[t] : 0;
    sm[t] = v;
    __syncthreads();
    int acc = v;
    for (int off = 1; off < 1024; off <<= 1) {
        int u = (t >= off) ? sm[t - off] : 0;
        __syncthreads();
        acc += u;
        sm[t] = acc;
        __syncthreads();
    }
    if (t < nbk) { bo[t] = acc - v; bcur[t] = acc - v; }
    if (t == 0) bo[nbk] = e;
}

// ---------------- two-phase pair scatter, packed (src<<7 | dst&127) ----------------
__global__ __launch_bounds__(256) void k_pair2(const int* __restrict__ src, const int* __restrict__ dst,
                                               int* __restrict__ bcur, unsigned int* __restrict__ pairs,
                                               int nbk, int e) {
    __shared__ int cnt[NBK_MAX];
    __shared__ int base[NBK_MAX];
    const int t = threadIdx.x;
    for (int b = t; b < nbk; b += 256) cnt[b] = 0;
    __syncthreads();
    const int e0 = blockIdx.x * EPB;
    int s[16], d[16], lo[16];
    #pragma unroll
    for (int j = 0; j < 16; ++j) {
        int idx = e0 + j * 256 + t;
        if (idx < e) {
            s[j] = src[idx];
            d[j] = dst[idx];
            lo[j] = atomicAdd(&cnt[d[j] >> BSH], 1);
        }
    }
    __syncthreads();
    for (int b = t; b < nbk; b += 256)
        base[b] = cnt[b] ? atomicAdd(&bcur[b], cnt[b]) : 0;
    __syncthreads();
    #pragma unroll
    for (int j = 0; j < 16; ++j) {
        int idx = e0 + j * 256 + t;
        if (idx < e)
            pairs[base[d[j] >> BSH] + lo[j]] = ((unsigned int)s[j] << 7) | (unsigned int)(d[j] & 127);
    }
}

// ---------------- fused BUILD: gemm blocks [0, ngemm) + CSR blocks [ngemm, ngemm+nbk) ----------------
// gemm no longer needs dinv (hs stored UNSCALED) -> independent of the CSR chain,
// so the ~12us CSR pass hides under the ~30us gemm. 512 threads, 68.6KB LDS, 2 blocks/CU.
__global__ __launch_bounds__(512, 4) void k_build(const float* __restrict__ x,
                                                  const _Float16* __restrict__ Wh,
                                                  __half* __restrict__ hs,
                                                  const unsigned int* __restrict__ pairs,
                                                  const int* __restrict__ bo,
                                                  int* __restrict__ rowptr, float* __restrict__ dinv,
                                                  unsigned int* __restrict__ dinvh,
                                                  int* __restrict__ csr_src,
                                                  int n, int e, int ngemm) {
    __shared__ _Float16 Ws[HID][WPAD];   // 67.6 KB (gemm part)
    __shared__ int cnt[128];             // (csr part)
    __shared__ int cur[128];
    const int tid = threadIdx.x;

    if ((int)blockIdx.x >= ngemm) {
        // ---------- CSR part: histogram + scan + rowptr/dinv/dinvh + fill ----------
        const int b = blockIdx.x - ngemm;
        if (tid < 128) cnt[tid] = 0;
        __syncthreads();
        const int beg = bo[b], end = bo[b + 1];
        for (int i = beg + tid; i < end; i += 512)
            atomicAdd(&cnt[pairs[i] & 127], 1);
        __syncthreads();
        if (tid < 128) cur[tid] = cnt[tid];
        __syncthreads();
        for (int off = 1; off < 128; off <<= 1) {
            int u = (tid < 128 && tid >= off) ? cur[tid - off] : 0;
            __syncthreads();
            if (tid < 128) cur[tid] += u;
            __syncthreads();
        }
        int myexcl = 0;
        const int node = (b << BSH) + tid;
        if (tid < 128) {
            myexcl = beg + cur[tid] - cnt[tid];
            if (node < n) {
                rowptr[node] = myexcl;
                float di = rsqrtf((float)(cnt[tid] + 1));   // +1 self loop
                dinv[node] = di;
                unsigned int hu = (unsigned int)__half_as_ushort(__float2half(di));
                dinvh[node] = hu * 0x10001u;                // broadcast to both halves
            }
        }
        if (b == 0 && tid == 0) rowptr[n] = e;
        __syncthreads();
        if (tid < 128) cur[tid] = myexcl;
        __syncthreads();
        for (int i = beg + tid; i < end; i += 512) {
            unsigned int pr = pairs[i];
            int p = atomicAdd(&cur[pr & 127], 1);
            csr_src[p] = (int)(pr >> 7);
        }
        return;
    }

    // ---------- GEMM part: W-in-LDS, barrier-free K-loop, fp16 MFMA, UNSCALED output ----------
    const int l   = tid & 63;
    const int w   = tid >> 6;            // 0..7
    const int fr  = l & 15;
    const int kg  = l >> 4;
    const int i0  = blockIdx.x * 128 + w * 16;

    const int r0 = i0 + fr;
    const float* xp = &x[(size_t)(r0 < n ? r0 : 0) * FIN + kg * 8];

    float4 xv[8][2];
    #pragma unroll
    for (int ks = 0; ks < 8; ++ks) {
        xv[ks][0] = *(const float4*)&xp[ks * 32];
        xv[ks][1] = *(const float4*)&xp[ks * 32 + 4];
    }

    #pragma unroll
    for (int j = 0; j < 8; ++j) {
        int c    = j * 512 + tid;
        int row  = c >> 5;
        int col8 = c & 31;
        *(half8v*)&Ws[row][col8 * 8] = *(const half8v*)&Wh[row * FIN + col8 * 8];
    }
    __syncthreads();

    f32x4 acc[8] = {};
    #pragma unroll
    for (int ks = 0; ks < 8; ++ks) {
        half8v ha;
        ha[0] = (_Float16)xv[ks][0].x; ha[1] = (_Float16)xv[ks][0].y;
        ha[2] = (_Float16)xv[ks][0].z; ha[3] = (_Float16)xv[ks][0].w;
        ha[4] = (_Float16)xv[ks][1].x; ha[5] = (_Float16)xv[ks][1].y;
        ha[6] = (_Float16)xv[ks][1].z; ha[7] = (_Float16)xv[ks][1].w;
        #pragma unroll
        for (int nt = 0; nt < 8; ++nt) {
            half8v hb = *(const half8v*)&Ws[nt * 16 + fr][kg * 8 + ks * 32];
            acc[nt] = __builtin_amdgcn_mfma_f32_16x16x32_f16(ha, hb, acc[nt], 0, 0, 0);
        }
    }

    // D(m,n): row = kg*4 + reg (M), col = nt*16 + fr (N)
    int rbase = i0 + kg * 4;
    if (rbase < n) {
        #pragma unroll
        for (int nt = 0; nt < 8; ++nt) {
            f32x4 c = acc[nt];
            int col = nt * 16 + fr;
            #pragma unroll
            for (int r = 0; r < 4; ++r) {
                int gi = rbase + r;
                if (gi < n)
                    hs[(size_t)gi * HID + col] = __float2half(((const float*)&c)[r]);
            }
        }
    }
}

// ---------------- layer-1 aggregation fused with layer-2 dot ----------------
// one wave per node; scalarized edge stream; per-edge dinv via packed __hfma2.
__global__ __launch_bounds__(256) void k_agg1(const unsigned int* __restrict__ hs,
                                              const int* __restrict__ rowptr,
                                              const int* __restrict__ csr_src,
                                              const float* __restrict__ dinv,
                                              const unsigned int* __restrict__ dinvh,
                                              const float* __restrict__ b1, const float* __restrict__ W2,
                                              float* __restrict__ zs, int n) {
    const int i = __builtin_amdgcn_readfirstlane((blockIdx.x << 2) + (threadIdx.x >> 6));
    if (i >= n) return;
    const int lane = threadIdx.x & 63;
    const float di = dinv[i];

    unsigned int sv = hs[((size_t)i << 6) + lane];         // self-loop term (unscaled)
    float2 sf = __half22float2(*reinterpret_cast<__half2*>(&sv));
    float ax = sf.x * di, ay = sf.y * di;

    __half2 acc0 = __float2half2_rn(0.f);
    __half2 acc1 = __float2half2_rn(0.f);

    const int beg = rowptr[i];
    const int end = rowptr[i + 1];
    int j = beg;
    for (; j + 8 <= end; j += 8) {
        int s[8];
        #pragma unroll
        for (int k = 0; k < 8; ++k) s[k] = csr_src[j + k];  // uniform -> s_load_dwordx8
        unsigned int v[8], dh[8];
        #pragma unroll
        for (int k = 0; k < 8; ++k) {
            dh[k] = dinvh[s[k]];                            // uniform -> s_load
            v[k]  = hs[((size_t)s[k] << 6) + lane];         // SGPR-base gather
        }
        #pragma unroll
        for (int k = 0; k < 8; ++k) {
            __half2 hv = *reinterpret_cast<__half2*>(&v[k]);
            __half2 dv = *reinterpret_cast<__half2*>(&dh[k]);
            if (k & 1) acc1 = __hfma2(hv, dv, acc1);
            else       acc0 = __hfma2(hv, dv, acc0);
        }
    }
    for (; j < end; ++j) {
        int s = csr_src[j];
        unsigned int dh = dinvh[s];
        unsigned int v = hs[((size_t)s << 6) + lane];
        acc0 = __hfma2(*reinterpret_cast<__half2*>(&v), *reinterpret_cast<__half2*>(&dh), acc0);
    }

    float2 f0 = __half22float2(acc0);
    float2 f1 = __half22float2(acc1);
    ax += f0.x + f1.x;
    ay += f0.y + f1.y;

    float2 bb = ((const float2*)b1)[lane];
    float h0 = fmaxf(ax * di + bb.x, 0.f);
    float h1 = fmaxf(ay * di + bb.y, 0.f);
    float2 w2 = ((const float2*)W2)[lane];
    float z = h0 * w2.x + h1 * w2.y;
    #pragma unroll
    for (int off = 32; off; off >>= 1) z += __shfl_xor(z, off, 64);
    if (lane == 0) zs[i] = z * di;
}

// ---------------- layer-2 aggregation ----------------
__global__ void k_agg2(const float* __restrict__ zs, const int* __restrict__ rowptr,
                       const int* __restrict__ csr_src, const float* __restrict__ dinv,
                       const float* __restrict__ b2, float* __restrict__ out, int n) {
    int i = blockIdx.x * blockDim.x + threadIdx.x;
    if (i >= n) return;
    float acc = zs[i];
    int beg = rowptr[i], end = rowptr[i + 1];
    for (int e = beg; e < end; ++e) acc += zs[csr_src[e]];
    out[i] = acc * dinv[i] + b2[0];
}

extern "C" void kernel_launch(void* const* d_in, const int* in_sizes, int n_in,
                              void* d_out, int out_size, void* d_ws, size_t ws_size,
                              hipStream_t stream) {
    const float* x  = (const float*)d_in[0];
    const int*   ei = (const int*)d_in[1];
    const float* W1 = (const float*)d_in[2];
    const float* b1 = (const float*)d_in[3];
    const float* W2 = (const float*)d_in[4];
    const float* b2 = (const float*)d_in[5];
    float* out = (float*)d_out;

    const int n = in_sizes[0] / FIN;
    const int e = in_sizes[1] / 2;
    const int* src = ei;
    const int* dst = ei + e;
    const int nbk = (n + (1 << BSH) - 1) >> BSH;
    const int ngemm = (n + 127) / 128;

    char* p = (char*)d_ws;
    auto carve = [&](size_t bytes) { char* q = p; p += (bytes + 255) & ~(size_t)255; return q; };
    int*            bcnt    = (int*)carve((size_t)NBK_MAX * 4);
    int*            bo      = (int*)carve((size_t)(NBK_MAX + 1) * 4);
    int*            bcur    = (int*)carve((size_t)NBK_MAX * 4);
    int*            rowptr  = (int*)carve((size_t)(n + 1) * 4);
    float*          dinv    = (float*)carve((size_t)n * 4);
    unsigned int*   dinvh   = (unsigned int*)carve((size_t)n * 4);
    int*            csr     = (int*)carve((size_t)e * 4);
    unsigned int*   pairs   = (unsigned int*)carve((size_t)e * 4);
    __half*         hs      = (__half*)carve((size_t)n * HID * 2);
    float*          zs      = (float*)carve((size_t)n * 4);
    _Float16*       Wh      = (_Float16*)carve((size_t)HID * FIN * 2);

    const int neb = (e + EPB - 1) / EPB;
    k_whalf<<<(HID * FIN + 255) / 256, 256, 0, stream>>>(W1, Wh, bcnt, HID * FIN);
    k_hist <<<neb, 256, 0, stream>>>(dst, bcnt, nbk, e);
    k_bscan<<<1, 1024, 0, stream>>>(bcnt, bo, bcur, nbk, e);
    k_pair2<<<neb, 256, 0, stream>>>(src, dst, bcur, pairs, nbk, e);
    k_build<<<ngemm + nbk, 512, 0, stream>>>(x, Wh, hs, pairs, bo, rowptr, dinv, dinvh, csr, n, e, ngemm);
    k_agg1 <<<(n + 3) / 4, 256, 0, stream>>>((const unsigned int*)hs, rowptr, csr, dinv, dinvh, b1, W2, zs, n);
    k_agg2 <<<(n + 255) / 256, 256, 0, stream>>>(zs, rowptr, csr, dinv, b2, out, n);
}